// Round 20
// baseline (184.220 us; speedup 1.0000x reference)
//
#include <hip/hip_runtime.h>
#include <stdint.h>

typedef unsigned short u16;
typedef __attribute__((ext_vector_type(8))) short short8;
typedef __attribute__((ext_vector_type(4))) short short4v;
typedef __attribute__((ext_vector_type(4))) float f32x4;

#define DEV static __device__ __forceinline__

constexpr int DMODEL = 1024;
constexpr int SEQ = 2048;

DEV u16 f2b(float f){
  uint32_t u = __float_as_uint(f);
  u += 0x7FFF + ((u >> 16) & 1);   // RNE to bf16
  return (u16)(u >> 16);
}

DEV float b2f(u16 b){ uint32_t u = ((uint32_t)b)<<16; return __uint_as_float(u); }

#define AS1(p) ((const __attribute__((address_space(1))) void*)(p))
#define AS3(p) ((__attribute__((address_space(3))) void*)(p))
#define GLOAD_LDS16(g, l) __builtin_amdgcn_global_load_lds(AS1(g), AS3(l), 16, 0, 0)
#define LDSADDR(p) ((uint32_t)(size_t)((__attribute__((address_space(3))) void*)(p)))

DEV short4v ds_tr16(uint32_t a){
  short4v r;
  asm volatile("ds_read_b64_tr_b16 %0, %1" : "=v"(r) : "v"(a) : "memory");
  return r;
}

DEV void pswap(uint32_t &a, uint32_t &b){
  asm("v_permlane32_swap_b32 %0, %1":"+v"(a),"+v"(b));
  asm("v_permlane16_swap_b32 %0, %1":"+v"(a),"+v"(b));
}

DEV uint32_t cvtpk(float lo, float hi){
  uint32_t r; asm("v_cvt_pk_bf16_f32 %0, %1, %2":"=v"(r):"v"(lo),"v"(hi)); return r;
}

// ------- prep: weight transposes (blocks 0..1535) + LN1 (blocks 1536..5631) --
__global__ __launch_bounds__(256) void prep_kernel(
    const float* __restrict__ wq, const float* __restrict__ wk,
    const float* __restrict__ wv, const float* __restrict__ wo,
    const float* __restrict__ w1, const float* __restrict__ w2,
    u16* __restrict__ WqkvT, u16* __restrict__ WoT,
    u16* __restrict__ W1T, u16* __restrict__ W2T,
    const float* __restrict__ x, const float* __restrict__ ln1g,
    const float* __restrict__ ln1b, u16* __restrict__ h1){
  int bid = blockIdx.x;
  if(bid >= 1536){
    // ---- LN1 row ----
    int row = bid - 1536, tid = threadIdx.x;
    const float4* x4 = (const float4*)(x + (size_t)row*DMODEL);
    float4 v = x4[tid];
    float s  = v.x+v.y+v.z+v.w;
    float ss = v.x*v.x + v.y*v.y + v.z*v.z + v.w*v.w;
    #pragma unroll
    for(int m=1;m<64;m<<=1){ s += __shfl_xor(s,m); ss += __shfl_xor(ss,m); }
    __shared__ float red[8];
    int w = tid>>6;
    if((tid&63)==0){ red[w]=s; red[4+w]=ss; }
    __syncthreads();
    s  = red[0]+red[1]+red[2]+red[3];
    ss = red[4]+red[5]+red[6]+red[7];
    float mu  = s*(1.f/DMODEL);
    float var = ss*(1.f/DMODEL) - mu*mu;
    float rs  = rsqrtf(var + 1e-5f);
    float4 gv = ((const float4*)ln1g)[tid];
    float4 bv = ((const float4*)ln1b)[tid];
    ushort4 o = make_ushort4(f2b((v.x-mu)*rs*gv.x+bv.x), f2b((v.y-mu)*rs*gv.y+bv.y),
                             f2b((v.z-mu)*rs*gv.z+bv.z), f2b((v.w-mu)*rs*gv.w+bv.w));
    ((ushort4*)h1)[(size_t)row*(DMODEL/4) + tid] = o;
    return;
  }
  // ---- weight transpose tile ----
  __shared__ float tile[64][65];
  int j = threadIdx.x & 63, i0 = threadIdx.x >> 6;
  if(bid < 768){
    int xb = bid & 15, z = bid >> 4;
    int p = z >> 4, h = z & 15;
    const float* src = (p==0?wq:(p==1?wk:wv)) + (size_t)h*1024*64;
    float sc = (p==0) ? 0.18033688011112042f : 1.0f;   // 0.125*log2(e)
    int r0 = xb*64;
    for(int i=i0;i<64;i+=4) tile[i][j] = src[(size_t)(r0+i)*64 + j];
    __syncthreads();
    u16* drow = WqkvT + ((size_t)p*1024 + h*64)*1024;
    for(int jj=i0;jj<64;jj+=4) drow[(size_t)jj*1024 + r0 + j] = f2b(tile[j][jj]*sc);
  } else {
    int t = bid - 768;
    int which = t >> 8; t &= 255;
    const float* src = which==0?wo:(which==1?w1:w2);
    u16* dst = which==0?WoT:(which==1?W1T:W2T);
    int r0 = (t&15)*64, c0 = (t>>4)*64;
    for(int i=i0;i<64;i+=4) tile[i][j] = src[(size_t)(r0+i)*1024 + c0 + j];
    __syncthreads();
    for(int jj=i0;jj<64;jj+=4) dst[(size_t)(c0+jj)*1024 + r0 + j] = f2b(tile[j][jj]);
  }
}

// ---------------- layernorm (bf16 input) ----------------
__global__ __launch_bounds__(256) void ln_kernel_bf(
    const u16* __restrict__ in, const float* __restrict__ g, const float* __restrict__ bb,
    u16* __restrict__ outb, float* __restrict__ outf){
  int row = blockIdx.x, tid = threadIdx.x;
  ushort4 vb = ((const ushort4*)(in + (size_t)row*DMODEL))[tid];
  float v0=b2f(vb.x), v1=b2f(vb.y), v2=b2f(vb.z), v3=b2f(vb.w);
  float s  = v0+v1+v2+v3;
  float ss = v0*v0 + v1*v1 + v2*v2 + v3*v3;
  #pragma unroll
  for(int m=1;m<64;m<<=1){ s += __shfl_xor(s,m); ss += __shfl_xor(ss,m); }
  __shared__ float red[8];
  int w = tid>>6;
  if((tid&63)==0){ red[w]=s; red[4+w]=ss; }
  __syncthreads();
  s  = red[0]+red[1]+red[2]+red[3];
  ss = red[4]+red[5]+red[6]+red[7];
  float mu  = s*(1.f/DMODEL);
  float var = ss*(1.f/DMODEL) - mu*mu;
  float rs  = rsqrtf(var + 1e-5f);
  float4 gv = ((const float4*)g)[tid];
  float4 bv = ((const float4*)bb)[tid];
  float y0=(v0-mu)*rs*gv.x+bv.x, y1=(v1-mu)*rs*gv.y+bv.y;
  float y2=(v2-mu)*rs*gv.z+bv.z, y3=(v3-mu)*rs*gv.w+bv.w;
  if(outb){ ushort4 o = make_ushort4(f2b(y0),f2b(y1),f2b(y2),f2b(y3));
            ((ushort4*)outb)[(size_t)row*(DMODEL/4) + tid] = o; }
  if(outf){ ((float4*)outf)[(size_t)row*(DMODEL/4) + tid] = make_float4(y0,y1,y2,y3); }
}

// ---------------- bf16 GEMM (BK=64, XOR-swizzled LDS) ----------------------
// 128x128 tile, BK=64 -> K/64 steps (halved barrier-drain events vs BK=32).
// 128B LDS rows would be 32-way conflicts; the attn-proven XOR swizzle
// (pre-swizzled global source + XOR'd b128 frag reads) makes reads 2-way.
// MODE 1: qkv scatter (hoisted base); 3: relu->bf16;
// MODE 5: bf16 = acc + res(f32); 6: bf16 = acc + res(bf16)
template<int MODE>
__global__ __launch_bounds__(256) void gemm_bt64(
    const u16* __restrict__ A, const u16* __restrict__ BT, int M, int N, int K,
    u16* __restrict__ outb, const float* __restrict__ resf, const u16* __restrict__ resb,
    u16* __restrict__ oq, u16* __restrict__ ok, u16* __restrict__ ov){
  __shared__ u16 lsA[2][8192];   // 128 x 64, swizzled content
  __shared__ u16 lsB[2][8192];
  int n0 = blockIdx.x*128, m0 = blockIdx.y*128;
  int tid = threadIdx.x, lane = tid&63, w = tid>>6;
  int wr = w>>1, wc = w&1, rq = lane&15, hk = lane>>4;
  const uint32_t sw = (uint32_t)((rq&7)<<4);
  const u16* aS[4]; const u16* bS[4];
  #pragma unroll
  for(int i=0;i<4;++i){
    int c = i*256 + tid;
    int o = c*16, row = o>>7;
    int bc = (o&127) ^ ((row&7)<<4);
    aS[i] = A  + (size_t)(m0+row)*K + (bc>>1);
    bS[i] = BT + (size_t)(n0+row)*K + (bc>>1);
  }
  int nk = K>>6;
  f32x4 acc[4][4] = {};
  #pragma unroll
  for(int i=0;i<4;++i){
    GLOAD_LDS16(aS[i], &lsA[0][i*2048 + w*512]);
    GLOAD_LDS16(bS[i], &lsB[0][i*2048 + w*512]);
  }
  #pragma unroll 2
  for(int kt=0; kt<nk; ++kt){
    __syncthreads();
    if(kt+1 < nk){
      int nb = (kt+1)&1;
      #pragma unroll
      for(int i=0;i<4;++i){
        GLOAD_LDS16(aS[i] + (kt+1)*64, &lsA[nb][i*2048 + w*512]);
        GLOAD_LDS16(bS[i] + (kt+1)*64, &lsB[nb][i*2048 + w*512]);
      }
    }
    const char* la = (const char*)&lsA[kt&1][0];
    const char* lb = (const char*)&lsB[kt&1][0];
    short8 aF[4][2], bF[4][2];
    #pragma unroll
    for(int m=0;m<4;++m){
      uint32_t rb = (uint32_t)((wr*64 + m*16 + rq)*128);
      aF[m][0] = *(const short8*)(la + rb + (((uint32_t)(hk<<4)) ^ sw));
      aF[m][1] = *(const short8*)(la + rb + ((64u|(uint32_t)(hk<<4)) ^ sw));
    }
    #pragma unroll
    for(int n=0;n<4;++n){
      uint32_t rb = (uint32_t)((wc*64 + n*16 + rq)*128);
      bF[n][0] = *(const short8*)(lb + rb + (((uint32_t)(hk<<4)) ^ sw));
      bF[n][1] = *(const short8*)(lb + rb + ((64u|(uint32_t)(hk<<4)) ^ sw));
    }
    __builtin_amdgcn_s_setprio(1);
    #pragma unroll
    for(int kk=0;kk<2;++kk){
      #pragma unroll
      for(int m=0;m<4;++m){
        #pragma unroll
        for(int n=0;n<4;++n)
          acc[m][n] = __builtin_amdgcn_mfma_f32_16x16x32_bf16(aF[m][kk], bF[n][kk], acc[m][n], 0,0,0);
      }
    }
    __builtin_amdgcn_s_setprio(0);
  }
  if constexpr(MODE==1){
    // hoisted scatter: proj/h/b/si-base are per-thread constants
    int proj = n0 >> 10;
    u16* dsel = proj==0?oq:(proj==1?ok:ov);
    int h0 = ((n0 & 1023) >> 6) + wc;
    int bb = m0 >> 11;
    int si0 = (m0 & 2047) + wr*64 + hk*4;
    u16* obase = dsel + (((size_t)(bb*16 + h0))*SEQ + si0)*64 + rq;
    #pragma unroll
    for(int m=0;m<4;++m){
      #pragma unroll
      for(int n=0;n<4;++n){
        #pragma unroll
        for(int qq=0;qq<4;++qq)
          obase[(size_t)(m*16+qq)*64 + n*16] = f2b(acc[m][n][qq]);
      }
    }
  } else {
    #pragma unroll
    for(int m=0;m<4;++m){
      #pragma unroll
      for(int n=0;n<4;++n){
        int rb = m0 + wr*64 + m*16 + (hk<<2);
        int c  = n0 + wc*64 + n*16 + rq;
        #pragma unroll
        for(int qq=0;qq<4;++qq){
          int r = rb+qq; float val = acc[m][n][qq];
          if constexpr(MODE==3){
            outb[(size_t)r*N + c] = f2b(val>0.f?val:0.f);
          } else if constexpr(MODE==5){
            outb[(size_t)r*N + c] = f2b(val + resf[(size_t)r*N + c]);
          } else {   // MODE 6
            outb[(size_t)r*N + c] = f2b(val + b2f(resb[(size_t)r*N + c]));
          }
        }
      }
    }
  }
}

// ---------------- flash attention v13 (measured-best, verbatim) ------------
// grid (B*H=32, S/128=16), block 512 = 8 waves (16 q-rows each). XCD-local bh
// mapping; 4-deep LDS ring, 1 barrier / 2 tiles.
__global__ __launch_bounds__(512) void attn_kernel(
    const u16* __restrict__ q, const u16* __restrict__ k, const u16* __restrict__ v,
    u16* __restrict__ concat){
  __shared__ u16 lsK[4][4096];
  __shared__ u16 lsV[4][4096];
  int bh = blockIdx.x, qt = blockIdx.y;   // XCD-local: xcd = linearId%8 = bh%8
  const u16* qp = q + (size_t)bh*SEQ*64;
  const u16* kp = k + (size_t)bh*SEQ*64;
  const u16* vp = v + (size_t)bh*SEQ*64;
  int tid=threadIdx.x, lane=tid&63, w=tid>>6;   // w 0..7
  int rq = lane&15, hk = lane>>4;
  const uint32_t sw = (uint32_t)((rq&7)<<4);

  short8 aQ[2];
  {
    const u16* qrow = qp + (size_t)(qt*128 + w*16 + rq)*64 + hk*8;
    aQ[0] = *(const short8*)(qrow);
    aQ[1] = *(const short8*)(qrow + 32);
  }
  short8 bOnes;
  #pragma unroll
  for(int j=0;j<8;++j) bOnes[j] = (short)0x3F80;

  int o = tid*16, kr = o>>7;                        // kr 0..63
  int koff = kr*64 + ((((o&127) ^ ((kr&7)<<4)))>>1);
  int vt  = ((tid>>5)<<2) | ((tid&7)>>1);           // 0..63
  int vd8 = (((tid>>3)&3)<<1) | (tid&1);            // 0..7
  int voff = vt*64 + vd8*8;

  f32x4 accO[4] = {};
  f32x4 accL = {};

  GLOAD_LDS16(kp + koff,        &lsK[0][w*512]);
  GLOAD_LDS16(vp + voff,        &lsV[0][w*512]);
  GLOAD_LDS16(kp + 4096 + koff, &lsK[1][w*512]);
  GLOAD_LDS16(vp + 4096 + voff, &lsV[1][w*512]);

  for(int it=0; it<SEQ/64; it+=2){
    __syncthreads();
    if(it+2 < SEQ/64){
      GLOAD_LDS16(kp + (it+2)*4096 + koff, &lsK[(it+2)&3][w*512]);
      GLOAD_LDS16(vp + (it+2)*4096 + voff, &lsV[(it+2)&3][w*512]);
      GLOAD_LDS16(kp + (it+3)*4096 + koff, &lsK[(it+3)&3][w*512]);
      GLOAD_LDS16(vp + (it+3)*4096 + voff, &lsV[(it+3)&3][w*512]);
    }
    #pragma unroll
    for(int sub=0; sub<2; ++sub){
      int t = it + sub;
      const char* kb = (const char*)&lsK[t&3][0];
      short8 bK[4][2];
      #pragma unroll
      for(int ts=0;ts<4;++ts){
        uint32_t rb = (uint32_t)((ts*16+rq)*128);
        bK[ts][0] = *(const short8*)(kb + rb + (((uint32_t)(hk<<4)) ^ sw));
        bK[ts][1] = *(const short8*)(kb + rb + ((64u|(uint32_t)(hk<<4)) ^ sw));
      }
      f32x4 z[4];
      __builtin_amdgcn_s_setprio(1);
      #pragma unroll
      for(int ts=0;ts<4;++ts){
        f32x4 zz = {};
        zz = __builtin_amdgcn_mfma_f32_16x16x32_bf16(bK[ts][0], aQ[0], zz, 0,0,0);
        zz = __builtin_amdgcn_mfma_f32_16x16x32_bf16(bK[ts][1], aQ[1], zz, 0,0,0);
        z[ts] = zz;
      }
      __builtin_amdgcn_s_setprio(0);
      uint32_t vA = LDSADDR(&lsV[t&3][0]) + (uint32_t)(hk*1024 + rq*2);
      short4v vL[2][4][2];
      #pragma unroll
      for(int kh=0;kh<2;++kh){
        #pragma unroll
        for(int ds=0;ds<4;++ds){
          vL[kh][ds][0] = ds_tr16(vA + kh*4096 + ds*128);
          vL[kh][ds][1] = ds_tr16(vA + kh*4096 + ds*128 + 512);
        }
      }
      #pragma unroll
      for(int ts=0;ts<4;++ts){
        #pragma unroll
        for(int r=0;r<4;++r)
          z[ts][r] = __builtin_exp2f(z[ts][r]);
      }
      uint32_t u00=cvtpk(z[0][0],z[0][1]), u01=cvtpk(z[0][2],z[0][3]);
      uint32_t u10=cvtpk(z[1][0],z[1][1]), u11=cvtpk(z[1][2],z[1][3]);
      uint32_t u20=cvtpk(z[2][0],z[2][1]), u21=cvtpk(z[2][2],z[2][3]);
      uint32_t u30=cvtpk(z[3][0],z[3][1]), u31=cvtpk(z[3][2],z[3][3]);
      pswap(u00,u10); pswap(u01,u11);   // kh=0
      pswap(u20,u30); pswap(u21,u31);   // kh=1
      union U8 { uint32_t d[4]; short8 v; } ap0, ap1;
      ap0.d[0]=u00; ap0.d[1]=u01; ap0.d[2]=u10; ap0.d[3]=u11;
      ap1.d[0]=u20; ap1.d[1]=u21; ap1.d[2]=u30; ap1.d[3]=u31;
      asm volatile("s_waitcnt lgkmcnt(0)" ::: "memory");
      __builtin_amdgcn_sched_barrier(0);
      __builtin_amdgcn_s_setprio(1);
      #pragma unroll
      for(int kh=0;kh<2;++kh){
        short8 aP = kh ? ap1.v : ap0.v;
        accL = __builtin_amdgcn_mfma_f32_16x16x32_bf16(aP, bOnes, accL, 0,0,0);
        #pragma unroll
        for(int ds=0;ds<4;++ds){
          short8 bV = __builtin_shufflevector(vL[kh][ds][0], vL[kh][ds][1], 0,1,2,3,4,5,6,7);
          accO[ds] = __builtin_amdgcn_mfma_f32_16x16x32_bf16(aP, bV, accO[ds], 0,0,0);
        }
      }
      __builtin_amdgcn_s_setprio(0);
    }
  }
  int b = bh>>4, h = bh&15;
  #pragma unroll
  for(int r=0;r<4;++r){
    float inv = 1.f / accL[r];
    int si = qt*128 + w*16 + hk*4 + r;
    #pragma unroll
    for(int ds=0;ds<4;++ds){
      int c = h*64 + ds*16 + rq;
      concat[((size_t)b*SEQ + si)*DMODEL + c] = f2b(accO[ds][r] * inv);
    }
  }
}

// ---------------- host ----------------
extern "C" void kernel_launch(void* const* d_in, const int* in_sizes, int n_in,
                              void* d_out, int out_size, void* d_ws, size_t ws_size,
                              hipStream_t stream){
  (void)in_sizes; (void)n_in; (void)out_size; (void)ws_size;
  const float* x    = (const float*)d_in[0];
  const float* wq   = (const float*)d_in[1];
  const float* wk   = (const float*)d_in[2];
  const float* wv   = (const float*)d_in[3];
  const float* wo   = (const float*)d_in[4];
  const float* w1   = (const float*)d_in[5];
  const float* w2   = (const float*)d_in[6];
  const float* ln1g = (const float*)d_in[7];
  const float* ln1b = (const float*)d_in[8];
  const float* ln2g = (const float*)d_in[9];
  const float* ln2b = (const float*)d_in[10];
  const float* ln3g = (const float*)d_in[11];
  const float* ln3b = (const float*)d_in[12];
  float* out = (float*)d_out;

  char* ws = (char*)d_ws; size_t off = 0;
  auto alloc = [&](size_t b)->char*{ char* p = ws + off; off += (b + 255) & ~(size_t)255; return p; };
  u16*   WqkvT = (u16*)  alloc((size_t)3072*1024*2);
  u16*   WoT   = (u16*)  alloc((size_t)1024*1024*2);
  u16*   W1T   = (u16*)  alloc((size_t)1024*1024*2);
  u16*   W2T   = (u16*)  alloc((size_t)1024*1024*2);
  u16*   h1    = (u16*)  alloc((size_t)4096*1024*2);
  u16*   qb    = (u16*)  alloc((size_t)4194304*2);
  u16*   kb    = (u16*)  alloc((size_t)4194304*2);
  u16*   vb    = (u16*)  alloc((size_t)4194304*2);
  u16*   cc    = (u16*)  alloc((size_t)4096*1024*2);
  u16*   r1b   = (u16*)  alloc((size_t)4096*1024*2);
  u16*   h2b   = (u16*)  alloc((size_t)4096*1024*2);
  u16*   r2b   = (u16*)  alloc((size_t)4096*1024*2);
  u16*   ffn1  = h1;   // h1 dead after QKV gemm

  prep_kernel<<<5632,256,0,stream>>>(wq,wk,wv,wo,w1,w2, WqkvT,WoT,W1T,W2T,
                                     x, ln1g, ln1b, h1);
  gemm_bt64<1><<<dim3(24,32),256,0,stream>>>(h1,WqkvT,4096,3072,1024,
      nullptr,nullptr,nullptr, qb,kb,vb);
  attn_kernel<<<dim3(32,16),512,0,stream>>>(qb,kb,vb,cc);
  gemm_bt64<5><<<dim3(8,32),256,0,stream>>>(cc,WoT,4096,1024,1024,
      r1b,x,nullptr, nullptr,nullptr,nullptr);
  ln_kernel_bf<<<4096,256,0,stream>>>(r1b, ln2g, ln2b, h2b, nullptr);
  gemm_bt64<3><<<dim3(8,32),256,0,stream>>>(h2b,W1T,4096,1024,1024,
      ffn1,nullptr,nullptr, nullptr,nullptr,nullptr);
  gemm_bt64<6><<<dim3(8,32),256,0,stream>>>(ffn1,W2T,4096,1024,1024,
      r2b,nullptr,h2b, nullptr,nullptr,nullptr);
  ln_kernel_bf<<<4096,256,0,stream>>>(r2b, ln3g, ln3b, nullptr, out);
}

// Round 21
// 180.183 us; speedup vs baseline: 1.0224x; 1.0224x over previous
//
#include <hip/hip_runtime.h>
#include <stdint.h>

typedef unsigned short u16;
typedef __attribute__((ext_vector_type(8))) short short8;
typedef __attribute__((ext_vector_type(4))) short short4v;
typedef __attribute__((ext_vector_type(4))) float f32x4;

#define DEV static __device__ __forceinline__

constexpr int DMODEL = 1024;
constexpr int SEQ = 2048;

DEV u16 f2b(float f){
  uint32_t u = __float_as_uint(f);
  u += 0x7FFF + ((u >> 16) & 1);   // RNE to bf16
  return (u16)(u >> 16);
}

DEV float b2f(u16 b){ uint32_t u = ((uint32_t)b)<<16; return __uint_as_float(u); }

#define AS1(p) ((const __attribute__((address_space(1))) void*)(p))
#define AS3(p) ((__attribute__((address_space(3))) void*)(p))
#define GLOAD_LDS16(g, l) __builtin_amdgcn_global_load_lds(AS1(g), AS3(l), 16, 0, 0)
#define LDSADDR(p) ((uint32_t)(size_t)((__attribute__((address_space(3))) void*)(p)))

DEV short4v ds_tr16(uint32_t a){
  short4v r;
  asm volatile("ds_read_b64_tr_b16 %0, %1" : "=v"(r) : "v"(a) : "memory");
  return r;
}

DEV void pswap(uint32_t &a, uint32_t &b){
  asm("v_permlane32_swap_b32 %0, %1":"+v"(a),"+v"(b));
  asm("v_permlane16_swap_b32 %0, %1":"+v"(a),"+v"(b));
}

DEV uint32_t cvtpk(float lo, float hi){
  uint32_t r; asm("v_cvt_pk_bf16_f32 %0, %1, %2":"=v"(r):"v"(lo),"v"(hi)); return r;
}

// ------- prep: weight transposes (blocks 0..1535) + LN1 (blocks 1536..5631) --
__global__ __launch_bounds__(256) void prep_kernel(
    const float* __restrict__ wq, const float* __restrict__ wk,
    const float* __restrict__ wv, const float* __restrict__ wo,
    const float* __restrict__ w1, const float* __restrict__ w2,
    u16* __restrict__ WqkvT, u16* __restrict__ WoT,
    u16* __restrict__ W1T, u16* __restrict__ W2T,
    const float* __restrict__ x, const float* __restrict__ ln1g,
    const float* __restrict__ ln1b, u16* __restrict__ h1){
  int bid = blockIdx.x;
  if(bid >= 1536){
    // ---- LN1 row ----
    int row = bid - 1536, tid = threadIdx.x;
    const float4* x4 = (const float4*)(x + (size_t)row*DMODEL);
    float4 v = x4[tid];
    float s  = v.x+v.y+v.z+v.w;
    float ss = v.x*v.x + v.y*v.y + v.z*v.z + v.w*v.w;
    #pragma unroll
    for(int m=1;m<64;m<<=1){ s += __shfl_xor(s,m); ss += __shfl_xor(ss,m); }
    __shared__ float red[8];
    int w = tid>>6;
    if((tid&63)==0){ red[w]=s; red[4+w]=ss; }
    __syncthreads();
    s  = red[0]+red[1]+red[2]+red[3];
    ss = red[4]+red[5]+red[6]+red[7];
    float mu  = s*(1.f/DMODEL);
    float var = ss*(1.f/DMODEL) - mu*mu;
    float rs  = rsqrtf(var + 1e-5f);
    float4 gv = ((const float4*)ln1g)[tid];
    float4 bv = ((const float4*)ln1b)[tid];
    ushort4 o = make_ushort4(f2b((v.x-mu)*rs*gv.x+bv.x), f2b((v.y-mu)*rs*gv.y+bv.y),
                             f2b((v.z-mu)*rs*gv.z+bv.z), f2b((v.w-mu)*rs*gv.w+bv.w));
    ((ushort4*)h1)[(size_t)row*(DMODEL/4) + tid] = o;
    return;
  }
  // ---- weight transpose tile ----
  __shared__ float tile[64][65];
  int j = threadIdx.x & 63, i0 = threadIdx.x >> 6;
  if(bid < 768){
    int xb = bid & 15, z = bid >> 4;
    int p = z >> 4, h = z & 15;
    const float* src = (p==0?wq:(p==1?wk:wv)) + (size_t)h*1024*64;
    float sc = (p==0) ? 0.18033688011112042f : 1.0f;   // 0.125*log2(e)
    int r0 = xb*64;
    for(int i=i0;i<64;i+=4) tile[i][j] = src[(size_t)(r0+i)*64 + j];
    __syncthreads();
    u16* drow = WqkvT + ((size_t)p*1024 + h*64)*1024;
    for(int jj=i0;jj<64;jj+=4) drow[(size_t)jj*1024 + r0 + j] = f2b(tile[j][jj]*sc);
  } else {
    int t = bid - 768;
    int which = t >> 8; t &= 255;
    const float* src = which==0?wo:(which==1?w1:w2);
    u16* dst = which==0?WoT:(which==1?W1T:W2T);
    int r0 = (t&15)*64, c0 = (t>>4)*64;
    for(int i=i0;i<64;i+=4) tile[i][j] = src[(size_t)(r0+i)*1024 + c0 + j];
    __syncthreads();
    for(int jj=i0;jj<64;jj+=4) dst[(size_t)(c0+jj)*1024 + r0 + j] = f2b(tile[j][jj]);
  }
}

// ---------------- layernorm (bf16 input) ----------------
__global__ __launch_bounds__(256) void ln_kernel_bf(
    const u16* __restrict__ in, const float* __restrict__ g, const float* __restrict__ bb,
    u16* __restrict__ outb, float* __restrict__ outf){
  int row = blockIdx.x, tid = threadIdx.x;
  ushort4 vb = ((const ushort4*)(in + (size_t)row*DMODEL))[tid];
  float v0=b2f(vb.x), v1=b2f(vb.y), v2=b2f(vb.z), v3=b2f(vb.w);
  float s  = v0+v1+v2+v3;
  float ss = v0*v0 + v1*v1 + v2*v2 + v3*v3;
  #pragma unroll
  for(int m=1;m<64;m<<=1){ s += __shfl_xor(s,m); ss += __shfl_xor(ss,m); }
  __shared__ float red[8];
  int w = tid>>6;
  if((tid&63)==0){ red[w]=s; red[4+w]=ss; }
  __syncthreads();
  s  = red[0]+red[1]+red[2]+red[3];
  ss = red[4]+red[5]+red[6]+red[7];
  float mu  = s*(1.f/DMODEL);
  float var = ss*(1.f/DMODEL) - mu*mu;
  float rs  = rsqrtf(var + 1e-5f);
  float4 gv = ((const float4*)g)[tid];
  float4 bv = ((const float4*)bb)[tid];
  float y0=(v0-mu)*rs*gv.x+bv.x, y1=(v1-mu)*rs*gv.y+bv.y;
  float y2=(v2-mu)*rs*gv.z+bv.z, y3=(v3-mu)*rs*gv.w+bv.w;
  if(outb){ ushort4 o = make_ushort4(f2b(y0),f2b(y1),f2b(y2),f2b(y3));
            ((ushort4*)outb)[(size_t)row*(DMODEL/4) + tid] = o; }
  if(outf){ ((float4*)outf)[(size_t)row*(DMODEL/4) + tid] = make_float4(y0,y1,y2,y3); }
}

// ---------------- bf16 GEMM (BK=32): used for the QKV projection ----------
// 128x128 tile, 2-buffer dbuf, unroll-2 parity folding; 32KB LDS -> 3 blocks/CU
// at the 768-block QKV grid (BK=64's 64KB LDS drops this to 2/CU: measured
// regression, R20). MODE 1 only: qkv scatter with hoisted per-thread base.
template<int MODE>
__global__ __launch_bounds__(256) void gemm_bt(
    const u16* __restrict__ A, const u16* __restrict__ BT, int M, int N, int K,
    u16* __restrict__ oq, u16* __restrict__ ok, u16* __restrict__ ov){
  __shared__ u16 lsA[2][4096];
  __shared__ u16 lsB[2][4096];
  int n0 = blockIdx.x*128, m0 = blockIdx.y*128;
  int tid = threadIdx.x, lane = tid&63, w = tid>>6;
  int wr = w>>1, wc = w&1, rq = lane&15, hk = lane>>4;
  int o0 = tid*16, o1 = 4096 + tid*16;
  const u16* aS0 = A  + (size_t)(m0 + (o0>>6))*K + ((o0&63)>>1);
  const u16* aS1 = A  + (size_t)(m0 + (o1>>6))*K + ((o1&63)>>1);
  const u16* bS0 = BT + (size_t)(n0 + (o0>>6))*K + ((o0&63)>>1);
  const u16* bS1 = BT + (size_t)(n0 + (o1>>6))*K + ((o1&63)>>1);
  int nk = K>>5;
  f32x4 acc[4][4] = {};
  GLOAD_LDS16(aS0, &lsA[0][w*512]);
  GLOAD_LDS16(aS1, &lsA[0][2048 + w*512]);
  GLOAD_LDS16(bS0, &lsB[0][w*512]);
  GLOAD_LDS16(bS1, &lsB[0][2048 + w*512]);
  #pragma unroll 2
  for(int kt=0; kt<nk; ++kt){
    __syncthreads();
    if(kt+1 < nk){
      int nb = (kt+1)&1;
      GLOAD_LDS16(aS0 + (kt+1)*32, &lsA[nb][w*512]);
      GLOAD_LDS16(aS1 + (kt+1)*32, &lsA[nb][2048 + w*512]);
      GLOAD_LDS16(bS0 + (kt+1)*32, &lsB[nb][w*512]);
      GLOAD_LDS16(bS1 + (kt+1)*32, &lsB[nb][2048 + w*512]);
    }
    const u16* la = &lsA[kt&1][0];
    const u16* lb = &lsB[kt&1][0];
    short8 aF[4], bF[4];
    #pragma unroll
    for(int m=0;m<4;++m) aF[m] = *(const short8*)(la + (wr*64 + m*16 + rq)*32 + hk*8);
    #pragma unroll
    for(int n=0;n<4;++n) bF[n] = *(const short8*)(lb + (wc*64 + n*16 + rq)*32 + hk*8);
    __builtin_amdgcn_s_setprio(1);
    #pragma unroll
    for(int m=0;m<4;++m){
      #pragma unroll
      for(int n=0;n<4;++n)
        acc[m][n] = __builtin_amdgcn_mfma_f32_16x16x32_bf16(aF[m], bF[n], acc[m][n], 0,0,0);
    }
    __builtin_amdgcn_s_setprio(0);
  }
  // hoisted scatter: proj/h/b/si-base are per-thread constants
  int proj = n0 >> 10;                        // 0,1,2
  u16* dsel = proj==0?oq:(proj==1?ok:ov);
  int h0 = ((n0 & 1023) >> 6) + wc;           // head index
  int bb = m0 >> 11;                          // batch
  int si0 = (m0 & 2047) + wr*64 + hk*4;       // seq base for this thread
  u16* obase = dsel + (((size_t)(bb*16 + h0))*SEQ + si0)*64 + rq;
  #pragma unroll
  for(int m=0;m<4;++m){
    #pragma unroll
    for(int n=0;n<4;++n){
      #pragma unroll
      for(int qq=0;qq<4;++qq)
        obase[(size_t)(m*16+qq)*64 + n*16] = f2b(acc[m][n][qq]);
    }
  }
}

// ---------------- bf16 GEMM (BK=64, XOR-swizzled LDS): N=1024 GEMMs -------
// 1 block/CU regime: halved barrier-drain events are a pure win (R18).
// MODE 3: relu->bf16; 5: bf16 = acc + res(f32); 6: bf16 = acc + res(bf16)
template<int MODE>
__global__ __launch_bounds__(256) void gemm_bt64(
    const u16* __restrict__ A, const u16* __restrict__ BT, int M, int N, int K,
    u16* __restrict__ outb, const float* __restrict__ resf, const u16* __restrict__ resb){
  __shared__ u16 lsA[2][8192];   // 128 x 64, swizzled content
  __shared__ u16 lsB[2][8192];
  int n0 = blockIdx.x*128, m0 = blockIdx.y*128;
  int tid = threadIdx.x, lane = tid&63, w = tid>>6;
  int wr = w>>1, wc = w&1, rq = lane&15, hk = lane>>4;
  const uint32_t sw = (uint32_t)((rq&7)<<4);
  const u16* aS[4]; const u16* bS[4];
  #pragma unroll
  for(int i=0;i<4;++i){
    int c = i*256 + tid;
    int o = c*16, row = o>>7;
    int bc = (o&127) ^ ((row&7)<<4);
    aS[i] = A  + (size_t)(m0+row)*K + (bc>>1);
    bS[i] = BT + (size_t)(n0+row)*K + (bc>>1);
  }
  int nk = K>>6;   // 16
  f32x4 acc[4][4] = {};
  #pragma unroll
  for(int i=0;i<4;++i){
    GLOAD_LDS16(aS[i], &lsA[0][i*2048 + w*512]);
    GLOAD_LDS16(bS[i], &lsB[0][i*2048 + w*512]);
  }
  #pragma unroll 2
  for(int kt=0; kt<nk; ++kt){
    __syncthreads();
    if(kt+1 < nk){
      int nb = (kt+1)&1;
      #pragma unroll
      for(int i=0;i<4;++i){
        GLOAD_LDS16(aS[i] + (kt+1)*64, &lsA[nb][i*2048 + w*512]);
        GLOAD_LDS16(bS[i] + (kt+1)*64, &lsB[nb][i*2048 + w*512]);
      }
    }
    const char* la = (const char*)&lsA[kt&1][0];
    const char* lb = (const char*)&lsB[kt&1][0];
    short8 aF[4][2], bF[4][2];
    #pragma unroll
    for(int m=0;m<4;++m){
      uint32_t rb = (uint32_t)((wr*64 + m*16 + rq)*128);
      aF[m][0] = *(const short8*)(la + rb + (((uint32_t)(hk<<4)) ^ sw));
      aF[m][1] = *(const short8*)(la + rb + ((64u|(uint32_t)(hk<<4)) ^ sw));
    }
    #pragma unroll
    for(int n=0;n<4;++n){
      uint32_t rb = (uint32_t)((wc*64 + n*16 + rq)*128);
      bF[n][0] = *(const short8*)(lb + rb + (((uint32_t)(hk<<4)) ^ sw));
      bF[n][1] = *(const short8*)(lb + rb + ((64u|(uint32_t)(hk<<4)) ^ sw));
    }
    __builtin_amdgcn_s_setprio(1);
    #pragma unroll
    for(int kk=0;kk<2;++kk){
      #pragma unroll
      for(int m=0;m<4;++m){
        #pragma unroll
        for(int n=0;n<4;++n)
          acc[m][n] = __builtin_amdgcn_mfma_f32_16x16x32_bf16(aF[m][kk], bF[n][kk], acc[m][n], 0,0,0);
      }
    }
    __builtin_amdgcn_s_setprio(0);
  }
  #pragma unroll
  for(int m=0;m<4;++m){
    #pragma unroll
    for(int n=0;n<4;++n){
      int rb = m0 + wr*64 + m*16 + (hk<<2);
      int c  = n0 + wc*64 + n*16 + rq;
      #pragma unroll
      for(int qq=0;qq<4;++qq){
        int r = rb+qq; float val = acc[m][n][qq];
        if constexpr(MODE==3){
          outb[(size_t)r*N + c] = f2b(val>0.f?val:0.f);
        } else if constexpr(MODE==5){
          outb[(size_t)r*N + c] = f2b(val + resf[(size_t)r*N + c]);
        } else {   // MODE 6
          outb[(size_t)r*N + c] = f2b(val + b2f(resb[(size_t)r*N + c]));
        }
      }
    }
  }
}

// ---------------- flash attention v13 (measured-best, verbatim) ------------
// grid (B*H=32, S/128=16), block 512 = 8 waves (16 q-rows each). XCD-local bh
// mapping; 4-deep LDS ring, 1 barrier / 2 tiles.
__global__ __launch_bounds__(512) void attn_kernel(
    const u16* __restrict__ q, const u16* __restrict__ k, const u16* __restrict__ v,
    u16* __restrict__ concat){
  __shared__ u16 lsK[4][4096];
  __shared__ u16 lsV[4][4096];
  int bh = blockIdx.x, qt = blockIdx.y;   // XCD-local: xcd = linearId%8 = bh%8
  const u16* qp = q + (size_t)bh*SEQ*64;
  const u16* kp = k + (size_t)bh*SEQ*64;
  const u16* vp = v + (size_t)bh*SEQ*64;
  int tid=threadIdx.x, lane=tid&63, w=tid>>6;   // w 0..7
  int rq = lane&15, hk = lane>>4;
  const uint32_t sw = (uint32_t)((rq&7)<<4);

  short8 aQ[2];
  {
    const u16* qrow = qp + (size_t)(qt*128 + w*16 + rq)*64 + hk*8;
    aQ[0] = *(const short8*)(qrow);
    aQ[1] = *(const short8*)(qrow + 32);
  }
  short8 bOnes;
  #pragma unroll
  for(int j=0;j<8;++j) bOnes[j] = (short)0x3F80;

  int o = tid*16, kr = o>>7;                        // kr 0..63
  int koff = kr*64 + ((((o&127) ^ ((kr&7)<<4)))>>1);
  int vt  = ((tid>>5)<<2) | ((tid&7)>>1);           // 0..63
  int vd8 = (((tid>>3)&3)<<1) | (tid&1);            // 0..7
  int voff = vt*64 + vd8*8;

  f32x4 accO[4] = {};
  f32x4 accL = {};

  GLOAD_LDS16(kp + koff,        &lsK[0][w*512]);
  GLOAD_LDS16(vp + voff,        &lsV[0][w*512]);
  GLOAD_LDS16(kp + 4096 + koff, &lsK[1][w*512]);
  GLOAD_LDS16(vp + 4096 + voff, &lsV[1][w*512]);

  for(int it=0; it<SEQ/64; it+=2){
    __syncthreads();
    if(it+2 < SEQ/64){
      GLOAD_LDS16(kp + (it+2)*4096 + koff, &lsK[(it+2)&3][w*512]);
      GLOAD_LDS16(vp + (it+2)*4096 + voff, &lsV[(it+2)&3][w*512]);
      GLOAD_LDS16(kp + (it+3)*4096 + koff, &lsK[(it+3)&3][w*512]);
      GLOAD_LDS16(vp + (it+3)*4096 + voff, &lsV[(it+3)&3][w*512]);
    }
    #pragma unroll
    for(int sub=0; sub<2; ++sub){
      int t = it + sub;
      const char* kb = (const char*)&lsK[t&3][0];
      short8 bK[4][2];
      #pragma unroll
      for(int ts=0;ts<4;++ts){
        uint32_t rb = (uint32_t)((ts*16+rq)*128);
        bK[ts][0] = *(const short8*)(kb + rb + (((uint32_t)(hk<<4)) ^ sw));
        bK[ts][1] = *(const short8*)(kb + rb + ((64u|(uint32_t)(hk<<4)) ^ sw));
      }
      f32x4 z[4];
      __builtin_amdgcn_s_setprio(1);
      #pragma unroll
      for(int ts=0;ts<4;++ts){
        f32x4 zz = {};
        zz = __builtin_amdgcn_mfma_f32_16x16x32_bf16(bK[ts][0], aQ[0], zz, 0,0,0);
        zz = __builtin_amdgcn_mfma_f32_16x16x32_bf16(bK[ts][1], aQ[1], zz, 0,0,0);
        z[ts] = zz;
      }
      __builtin_amdgcn_s_setprio(0);
      uint32_t vA = LDSADDR(&lsV[t&3][0]) + (uint32_t)(hk*1024 + rq*2);
      short4v vL[2][4][2];
      #pragma unroll
      for(int kh=0;kh<2;++kh){
        #pragma unroll
        for(int ds=0;ds<4;++ds){
          vL[kh][ds][0] = ds_tr16(vA + kh*4096 + ds*128);
          vL[kh][ds][1] = ds_tr16(vA + kh*4096 + ds*128 + 512);
        }
      }
      #pragma unroll
      for(int ts=0;ts<4;++ts){
        #pragma unroll
        for(int r=0;r<4;++r)
          z[ts][r] = __builtin_exp2f(z[ts][r]);
      }
      uint32_t u00=cvtpk(z[0][0],z[0][1]), u01=cvtpk(z[0][2],z[0][3]);
      uint32_t u10=cvtpk(z[1][0],z[1][1]), u11=cvtpk(z[1][2],z[1][3]);
      uint32_t u20=cvtpk(z[2][0],z[2][1]), u21=cvtpk(z[2][2],z[2][3]);
      uint32_t u30=cvtpk(z[3][0],z[3][1]), u31=cvtpk(z[3][2],z[3][3]);
      pswap(u00,u10); pswap(u01,u11);   // kh=0
      pswap(u20,u30); pswap(u21,u31);   // kh=1
      union U8 { uint32_t d[4]; short8 v; } ap0, ap1;
      ap0.d[0]=u00; ap0.d[1]=u01; ap0.d[2]=u10; ap0.d[3]=u11;
      ap1.d[0]=u20; ap1.d[1]=u21; ap1.d[2]=u30; ap1.d[3]=u31;
      asm volatile("s_waitcnt lgkmcnt(0)" ::: "memory");
      __builtin_amdgcn_sched_barrier(0);
      __builtin_amdgcn_s_setprio(1);
      #pragma unroll
      for(int kh=0;kh<2;++kh){
        short8 aP = kh ? ap1.v : ap0.v;
        accL = __builtin_amdgcn_mfma_f32_16x16x32_bf16(aP, bOnes, accL, 0,0,0);
        #pragma unroll
        for(int ds=0;ds<4;++ds){
          short8 bV = __builtin_shufflevector(vL[kh][ds][0], vL[kh][ds][1], 0,1,2,3,4,5,6,7);
          accO[ds] = __builtin_amdgcn_mfma_f32_16x16x32_bf16(aP, bV, accO[ds], 0,0,0);
        }
      }
      __builtin_amdgcn_s_setprio(0);
    }
  }
  int b = bh>>4, h = bh&15;
  #pragma unroll
  for(int r=0;r<4;++r){
    float inv = 1.f / accL[r];
    int si = qt*128 + w*16 + hk*4 + r;
    #pragma unroll
    for(int ds=0;ds<4;++ds){
      int c = h*64 + ds*16 + rq;
      concat[((size_t)b*SEQ + si)*DMODEL + c] = f2b(accO[ds][r] * inv);
    }
  }
}

// ---------------- host ----------------
extern "C" void kernel_launch(void* const* d_in, const int* in_sizes, int n_in,
                              void* d_out, int out_size, void* d_ws, size_t ws_size,
                              hipStream_t stream){
  (void)in_sizes; (void)n_in; (void)out_size; (void)ws_size;
  const float* x    = (const float*)d_in[0];
  const float* wq   = (const float*)d_in[1];
  const float* wk   = (const float*)d_in[2];
  const float* wv   = (const float*)d_in[3];
  const float* wo   = (const float*)d_in[4];
  const float* w1   = (const float*)d_in[5];
  const float* w2   = (const float*)d_in[6];
  const float* ln1g = (const float*)d_in[7];
  const float* ln1b = (const float*)d_in[8];
  const float* ln2g = (const float*)d_in[9];
  const float* ln2b = (const float*)d_in[10];
  const float* ln3g = (const float*)d_in[11];
  const float* ln3b = (const float*)d_in[12];
  float* out = (float*)d_out;

  char* ws = (char*)d_ws; size_t off = 0;
  auto alloc = [&](size_t b)->char*{ char* p = ws + off; off += (b + 255) & ~(size_t)255; return p; };
  u16*   WqkvT = (u16*)  alloc((size_t)3072*1024*2);
  u16*   WoT   = (u16*)  alloc((size_t)1024*1024*2);
  u16*   W1T   = (u16*)  alloc((size_t)1024*1024*2);
  u16*   W2T   = (u16*)  alloc((size_t)1024*1024*2);
  u16*   h1    = (u16*)  alloc((size_t)4096*1024*2);
  u16*   qb    = (u16*)  alloc((size_t)4194304*2);
  u16*   kb    = (u16*)  alloc((size_t)4194304*2);
  u16*   vb    = (u16*)  alloc((size_t)4194304*2);
  u16*   cc    = (u16*)  alloc((size_t)4096*1024*2);
  u16*   r1b   = (u16*)  alloc((size_t)4096*1024*2);
  u16*   h2b   = (u16*)  alloc((size_t)4096*1024*2);
  u16*   r2b   = (u16*)  alloc((size_t)4096*1024*2);
  u16*   ffn1  = h1;   // h1 dead after QKV gemm

  prep_kernel<<<5632,256,0,stream>>>(wq,wk,wv,wo,w1,w2, WqkvT,WoT,W1T,W2T,
                                     x, ln1g, ln1b, h1);
  gemm_bt<1><<<dim3(24,32),256,0,stream>>>(h1,WqkvT,4096,3072,1024, qb,kb,vb);
  attn_kernel<<<dim3(32,16),512,0,stream>>>(qb,kb,vb,cc);
  gemm_bt64<5><<<dim3(8,32),256,0,stream>>>(cc,WoT,4096,1024,1024, r1b,x,nullptr);
  ln_kernel_bf<<<4096,256,0,stream>>>(r1b, ln2g, ln2b, h2b, nullptr);
  gemm_bt64<3><<<dim3(8,32),256,0,stream>>>(h2b,W1T,4096,1024,1024, ffn1,nullptr,nullptr);
  gemm_bt64<6><<<dim3(8,32),256,0,stream>>>(ffn1,W2T,4096,1024,1024, r2b,nullptr,h2b);
  ln_kernel_bf<<<4096,256,0,stream>>>(r2b, ln3g, ln3b, nullptr, out);
}